// Round 15
// baseline (148.941 us; speedup 1.0000x reference)
//
#include <hip/hip_runtime.h>
#include <math.h>

#define TLEN 4096
#define NB   1024
#define NS   10
#define KC   64
#define NCHK 16
#define BUF_U32 10240   // XB 5120 | AS 5120 (u32 units, 40 KB)

typedef __attribute__((ext_vector_type(8))) short s16x8;
typedef __attribute__((ext_vector_type(4))) float f32x4;
typedef __attribute__((ext_vector_type(2))) float f32x2;

static __device__ __forceinline__ unsigned cvtpk(float lo, float hi) {
  unsigned r;
  asm("v_cvt_pk_bf16_f32 %0, %1, %2" : "=v"(r) : "v"(lo), "v"(hi));
  return r;
}
static __device__ __forceinline__ int swz(int P, int L) {
  return P*64 + (L ^ ((P ^ (P >> 2)) & 7));
}
// LDS-only barrier: does NOT drain vmcnt -> global loads/stores stay in
// flight across it (all cross-thread handoffs here go through LDS).
static __device__ __forceinline__ void lbar() {
  asm volatile("s_waitcnt lgkmcnt(0)" ::: "memory");
  __builtin_amdgcn_s_barrier();
}

// Fused, 2 blocks per t-tile (grid 256x2): both run full-K phase 1 (S via
// MFMA, kept in LDS as packed bf16 pairs); phase 2 split by b-half.
__global__ __launch_bounds__(512) void fused_k(
    const float* __restrict__ x, const float* __restrict__ sa,
    const float* __restrict__ adj, const float* __restrict__ theta,
    float* __restrict__ out) {
  __shared__ __align__(16) unsigned buf[BUF_U32];   // 40 KB; phase2: stg
  __shared__ __align__(16) unsigned S2[16*52];      // [t][pp*10+nn] bf16-pairs
  __shared__ float ck[300];
  const int tid = threadIdx.x;
  const int l   = tid & 63;
  const int t0  = blockIdx.x * 16;

  const int w   = tid >> 6;
  const int bp  = tid / 10;
  const int rm  = tid - bp*10;
  const int q   = rm >> 1;
  const int th  = rm & 1;
  const int gq  = rm;
  const int ksx = bp >> 4;
  const int kgx = (bp & 15) >> 2;
  const int jwx = bp & 3;
  const int n0  = 2*w, n1 = 2*w + 1;

  f32x4 acc0 = {0.f,0.f,0.f,0.f}, acc1 = {0.f,0.f,0.f,0.f};
  f32x2 xlo[8], xhi[8], slo[5], shi[5];

  float pL[5][5], pv[5];
  if (tid == 320) {
    float Wm[5][5];
    #pragma unroll
    for (int r = 0; r < 5; ++r)
      #pragma unroll
      for (int c = 0; c < 5; ++c) Wm[r][c] = adj[r*5+c];
    #pragma unroll
    for (int r = 0; r < 5; ++r) {
      float d = 0.f;
      #pragma unroll
      for (int c = 0; c < 5; ++c) d += Wm[r][c];
      #pragma unroll
      for (int c = 0; c < 5; ++c) pL[r][c] = (r==c ? d : 0.f) - Wm[r][c];
    }
    pv[0]=0.7f; pv[1]=-1.1f; pv[2]=0.9f; pv[3]=-0.8f; pv[4]=1.3f;
  }

  // ---- prologue: load + stage chunk 0
  if (tid < 320) {
    const float* xb = x + (size_t)(t0 + th*8)*(NB*NS) + (size_t)(2*bp)*NS + 2*q;
    #pragma unroll
    for (int r = 0; r < 8; ++r) {
      xlo[r] = __builtin_nontemporal_load((const f32x2*)(xb + r*(NB*NS)));
      xhi[r] = __builtin_nontemporal_load((const f32x2*)(xb + r*(NB*NS) + NS));
    }
    const float* sb = sa + (size_t)(2*bp)*100 + gq*10;
    #pragma unroll
    for (int e = 0; e < 5; ++e) {
      slo[e] = *(const f32x2*)(sb + 2*e);
      shi[e] = *(const f32x2*)(sb + 100 + 2*e);
    }
    #pragma unroll
    for (int r = 0; r < 8; ++r) {
      const int L = kgx*16 + th*8 + r;
      buf[swz((2*q  )*2 + ksx, L)*4 + jwx] = cvtpk(xlo[r].x, xhi[r].x);
      buf[swz((2*q+1)*2 + ksx, L)*4 + jwx] = cvtpk(xlo[r].y, xhi[r].y);
    }
    #pragma unroll
    for (int e = 0; e < 5; ++e) {
      const int L = kgx*16 + gq;
      buf[5120 + swz((2*e  )*2 + ksx, L)*4 + jwx] = cvtpk(slo[e].x, shi[e].x);
      buf[5120 + swz((2*e+1)*2 + ksx, L)*4 + jwx] = cvtpk(slo[e].y, shi[e].y);
    }
  }

  for (int c = 0; c < NCHK; ++c) {
    lbar();                                // staged writes visible
    if (tid < 320) {
      if (c + 1 < NCHK) {                  // issue next chunk's loads early
        const int bc = (c+1)*KC;
        const float* xb = x + (size_t)(t0 + th*8)*(NB*NS)
                            + (size_t)(bc + 2*bp)*NS + 2*q;
        #pragma unroll
        for (int r = 0; r < 8; ++r) {
          xlo[r] = __builtin_nontemporal_load((const f32x2*)(xb + r*(NB*NS)));
          xhi[r] = __builtin_nontemporal_load((const f32x2*)(xb + r*(NB*NS) + NS));
        }
        const float* sb = sa + (size_t)(bc + 2*bp)*100 + gq*10;
        #pragma unroll
        for (int e = 0; e < 5; ++e) {
          slo[e] = *(const f32x2*)(sb + 2*e);
          shi[e] = *(const f32x2*)(sb + 100 + 2*e);
        }
      }
      const s16x8* XBf = (const s16x8*)buf;
      const s16x8* ASf = (const s16x8*)(buf + 5120);
      #pragma unroll
      for (int ks = 0; ks < 2; ++ks) {
        acc0 = __builtin_amdgcn_mfma_f32_16x16x32_bf16(
                 ASf[swz(n0*2+ks, l)], XBf[swz(n0*2+ks, l)], acc0, 0, 0, 0);
        acc1 = __builtin_amdgcn_mfma_f32_16x16x32_bf16(
                 ASf[swz(n1*2+ks, l)], XBf[swz(n1*2+ks, l)], acc1, 0, 0, 0);
      }
    } else if (tid == 320 && c < 12) {     // 8 power iters per chunk (96 total)
      #pragma unroll
      for (int it = 0; it < 8; ++it) {
        float wv[5];
        #pragma unroll
        for (int r = 0; r < 5; ++r) {
          float s = 0.f;
          #pragma unroll
          for (int cc = 0; cc < 5; ++cc) s += pL[r][cc]*pv[cc];
          wv[r] = s;
        }
        float s = fabsf(wv[0])+fabsf(wv[1])+fabsf(wv[2])+fabsf(wv[3])+fabsf(wv[4]);
        float inv = 1.f/s;
        #pragma unroll
        for (int r = 0; r < 5; ++r) pv[r] = wv[r]*inv;
      }
    }
    lbar();                                // buf frag-reads done
    if (tid < 320 && c + 1 < NCHK) {       // stage chunk c+1
      #pragma unroll
      for (int r = 0; r < 8; ++r) {
        const int L = kgx*16 + th*8 + r;
        buf[swz((2*q  )*2 + ksx, L)*4 + jwx] = cvtpk(xlo[r].x, xhi[r].x);
        buf[swz((2*q+1)*2 + ksx, L)*4 + jwx] = cvtpk(xlo[r].y, xhi[r].y);
      }
      #pragma unroll
      for (int e = 0; e < 5; ++e) {
        const int L = kgx*16 + gq;
        buf[5120 + swz((2*e  )*2 + ksx, L)*4 + jwx] = cvtpk(slo[e].x, shi[e].x);
        buf[5120 + swz((2*e+1)*2 + ksx, L)*4 + jwx] = cvtpk(slo[e].y, shi[e].y);
      }
    }
  }

  // ---- finalize k0 -> ck
  if (tid == 320) {
    float num = 0.f, den = 0.f;
    #pragma unroll
    for (int r = 0; r < 5; ++r) {
      float s = 0.f;
      #pragma unroll
      for (int cc = 0; cc < 5; ++cc) s += pL[r][cc]*pv[cc];
      num += pv[r]*s; den += pv[r]*pv[r];
    }
    const float lam = num/den;
    float Lt[5][5], T2[5][5];
    #pragma unroll
    for (int r = 0; r < 5; ++r)
      #pragma unroll
      for (int cc = 0; cc < 5; ++cc)
        Lt[r][cc] = 2.f*pL[r][cc]/lam - (r==cc ? 1.f : 0.f);
    #pragma unroll
    for (int r = 0; r < 5; ++r)
      #pragma unroll
      for (int cc = 0; cc < 5; ++cc) {
        float s = 0.f;
        #pragma unroll
        for (int j = 0; j < 5; ++j) s += Lt[r][j]*Lt[j][cc];
        T2[r][cc] = 2.f*s - (r==cc ? 1.f : 0.f);
      }
    #pragma unroll
    for (int p = 0; p < 10; ++p)
      #pragma unroll
      for (int nn = 0; nn < 10; ++nn) {
        const int m = (10*p+nn) % 25, r = m/5, cc = m%5;
        ck[0*100 + p*10+nn] = (r==cc ? 1.f : 0.f);
        ck[1*100 + p*10+nn] = Lt[r][cc];
        ck[2*100 + p*10+nn] = T2[r][cc];
      }
  }
  // ---- acc -> S2 packed bf16 pairs: S2[t*52 + pp*10 + n] = (p=2pp, p=2pp+1)
  if (tid < 320) {
    const int pg = (l >> 4) * 4;           // 0,4,8,12
    const int tl = l & 15;
    unsigned* srow = S2 + tl*52;
    const int pp0 = pg >> 1;
    if (pg < 10) {
      srow[pp0*10 + n0] = cvtpk(acc0[0], acc0[1]);
      srow[pp0*10 + n1] = cvtpk(acc1[0], acc1[1]);
    }
    if (pg + 2 < 10) {
      srow[(pp0+1)*10 + n0] = cvtpk(acc0[2], acc0[3]);
      srow[(pp0+1)*10 + n1] = cvtpk(acc1[2], acc1[3]);
    }
  }
  lbar();

  // ---- phase 2 (b-half per block): out[t,b,n] = relu(sum_p S * W[p,n,b])
  float* stg = (float*)buf;               // 2 x 5120 floats, double-buffered
  const int b    = blockIdx.y*512 + tid;
  const int yoff = blockIdx.y*5120;
  float W[10][10];
  #pragma unroll
  for (int p = 0; p < 10; ++p) {
    const float th0 = theta[          p*NB + b];
    const float th1 = theta[10*NB  +  p*NB + b];
    const float th2 = theta[20*NB  +  p*NB + b];
    #pragma unroll
    for (int nn = 0; nn < 10; ++nn)
      W[p][nn] = ck[p*10+nn]*th0 + ck[100+p*10+nn]*th1 + ck[200+p*10+nn]*th2;
  }
  for (int t = 0; t < 16; ++t) {
    float a0[10];
    #pragma unroll
    for (int nn = 0; nn < 10; ++nn) a0[nn] = 0.f;
    {
      const uint4* rp = (const uint4*)(S2 + t*52);
      uint4 rq[13];
      #pragma unroll
      for (int i = 0; i < 13; ++i) rq[i] = rp[i];
      #pragma unroll
      for (int j = 0; j < 50; ++j) {
        const int i = j >> 2, e = j & 3;
        const unsigned u = (e==0) ? rq[i].x : (e==1) ? rq[i].y
                         : (e==2) ? rq[i].z : rq[i].w;
        const int pp = j / 10, nn = j - pp*10;
        a0[nn] += __uint_as_float(u << 16)         * W[2*pp][nn]
                + __uint_as_float(u & 0xffff0000u) * W[2*pp+1][nn];
      }
    }
    float* sg = stg + (t & 1)*5120;
    #pragma unroll
    for (int nn = 0; nn < 10; ++nn)
      sg[tid*10 + nn] = fmaxf(a0[nn], 0.f);
    lbar();                               // sg visible (prev-prev reads done)
    const f32x4* sv = (const f32x4*)sg;
    f32x4* op = (f32x4*)(out + (size_t)(t0 + t)*(NB*NS) + yoff);
    __builtin_nontemporal_store(sv[tid],       op + tid);
    __builtin_nontemporal_store(sv[tid + 512], op + tid + 512);
    if (tid < 256)
      __builtin_nontemporal_store(sv[tid + 1024], op + tid + 1024);
  }
}

extern "C" void kernel_launch(void* const* d_in, const int* in_sizes, int n_in,
                              void* d_out, int out_size, void* d_ws, size_t ws_size,
                              hipStream_t stream) {
  const float* x   = (const float*)d_in[0];  // (4096,1024,10)
  const float* adj = (const float*)d_in[1];  // (5,5)
  const float* sa  = (const float*)d_in[2];  // (1024,10,10)
  const float* th  = (const float*)d_in[3];  // (3,10,1024)
  float* out = (float*)d_out;
  hipLaunchKernelGGL(fused_k, dim3(TLEN/16, 2), dim3(512), 0, stream,
                     x, sa, adj, th, out);
}

// Round 17
// 106.893 us; speedup vs baseline: 1.3934x; 1.3934x over previous
//
#include <hip/hip_runtime.h>
#include <math.h>

#define TLEN 4096
#define NB   1024
#define NS   10
#define KC   64
#define NCHK 16
#define TB   8          // t per block -> grid 512 = 2 blocks/CU
#define BUF_U32 10240   // XB 5120 | AS 5120 (u32 units, 40 KB)

typedef __attribute__((ext_vector_type(8))) short s16x8;
typedef __attribute__((ext_vector_type(4))) float f32x4;
typedef __attribute__((ext_vector_type(2))) float f32x2;

static __device__ __forceinline__ unsigned cvtpk(float lo, float hi) {
  unsigned r;
  asm("v_cvt_pk_bf16_f32 %0, %1, %2" : "=v"(r) : "v"(lo), "v"(hi));
  return r;
}
static __device__ __forceinline__ int swz(int P, int L) {
  return P*64 + (L ^ ((P ^ (P >> 2)) & 7));
}
// LDS-only barrier: no vmcnt drain (all cross-thread handoffs via LDS)
static __device__ __forceinline__ void lbar() {
  asm volatile("s_waitcnt lgkmcnt(0)" ::: "memory");
  __builtin_amdgcn_s_barrier();
}

// Fused, t-tile = 8, grid 512 (2 blocks/CU): S[n,p,t] = sum_b SA[b,p,n] *
// x[t,b,n] via MFMA (t-cols 8..15 of the 16x16 tile are discarded); S kept
// in LDS as packed bf16 pairs; out[t,b,n] = relu(sum_p S * W[p,n,b]).
__global__ __launch_bounds__(512) void fused_k(
    const float* __restrict__ x, const float* __restrict__ sa,
    const float* __restrict__ adj, const float* __restrict__ theta,
    float* __restrict__ out) {
  __shared__ __align__(16) unsigned buf[BUF_U32];   // 40 KB; phase2: stg
  __shared__ __align__(16) unsigned S2[TB*52];      // [t][pp*10+nn] bf16-pairs
  __shared__ float ck[300];
  const int tid = threadIdx.x;
  const int l   = tid & 63;
  const int t0  = blockIdx.x * TB;

  const int w   = tid >> 6;
  const int bp  = tid / 10;         // 0..31 b-pairs (tid<320)
  const int rm  = tid - bp*10;
  const int q   = rm >> 1;          // n-pair
  const int th  = rm & 1;           // t-quad
  const int gq  = rm;               // SA p-row
  const int ksx = bp >> 4;
  const int kgx = (bp & 15) >> 2;
  const int jwx = bp & 3;
  const int n0  = 2*w, n1 = 2*w + 1;

  f32x4 acc0 = {0.f,0.f,0.f,0.f}, acc1 = {0.f,0.f,0.f,0.f};
  f32x2 xlo[4], xhi[4], slo[5], shi[5];

  float pL[5][5], pv[5];
  if (tid == 320) {
    float Wm[5][5];
    #pragma unroll
    for (int r = 0; r < 5; ++r)
      #pragma unroll
      for (int c = 0; c < 5; ++c) Wm[r][c] = adj[r*5+c];
    #pragma unroll
    for (int r = 0; r < 5; ++r) {
      float d = 0.f;
      #pragma unroll
      for (int c = 0; c < 5; ++c) d += Wm[r][c];
      #pragma unroll
      for (int c = 0; c < 5; ++c) pL[r][c] = (r==c ? d : 0.f) - Wm[r][c];
    }
    pv[0]=0.7f; pv[1]=-1.1f; pv[2]=0.9f; pv[3]=-0.8f; pv[4]=1.3f;
  }

  // ---- prologue: load + stage chunk 0
  if (tid < 320) {
    const float* xb = x + (size_t)(t0 + th*4)*(NB*NS) + (size_t)(2*bp)*NS + 2*q;
    #pragma unroll
    for (int r = 0; r < 4; ++r) {
      xlo[r] = __builtin_nontemporal_load((const f32x2*)(xb + r*(NB*NS)));
      xhi[r] = __builtin_nontemporal_load((const f32x2*)(xb + r*(NB*NS) + NS));
    }
    const float* sb = sa + (size_t)(2*bp)*100 + gq*10;
    #pragma unroll
    for (int e = 0; e < 5; ++e) {
      slo[e] = *(const f32x2*)(sb + 2*e);
      shi[e] = *(const f32x2*)(sb + 100 + 2*e);
    }
    #pragma unroll
    for (int r = 0; r < 4; ++r) {
      const int L = kgx*16 + th*4 + r;
      buf[swz((2*q  )*2 + ksx, L)*4 + jwx] = cvtpk(xlo[r].x, xhi[r].x);
      buf[swz((2*q+1)*2 + ksx, L)*4 + jwx] = cvtpk(xlo[r].y, xhi[r].y);
    }
    #pragma unroll
    for (int e = 0; e < 5; ++e) {
      const int L = kgx*16 + gq;
      buf[5120 + swz((2*e  )*2 + ksx, L)*4 + jwx] = cvtpk(slo[e].x, shi[e].x);
      buf[5120 + swz((2*e+1)*2 + ksx, L)*4 + jwx] = cvtpk(slo[e].y, shi[e].y);
    }
  }

  for (int c = 0; c < NCHK; ++c) {
    lbar();                                // staged writes visible
    if (tid < 320) {
      if (c + 1 < NCHK) {                  // issue next chunk's loads early
        const int bc = (c+1)*KC;
        const float* xb = x + (size_t)(t0 + th*4)*(NB*NS)
                            + (size_t)(bc + 2*bp)*NS + 2*q;
        #pragma unroll
        for (int r = 0; r < 4; ++r) {
          xlo[r] = __builtin_nontemporal_load((const f32x2*)(xb + r*(NB*NS)));
          xhi[r] = __builtin_nontemporal_load((const f32x2*)(xb + r*(NB*NS) + NS));
        }
        const float* sb = sa + (size_t)(bc + 2*bp)*100 + gq*10;
        #pragma unroll
        for (int e = 0; e < 5; ++e) {
          slo[e] = *(const f32x2*)(sb + 2*e);
          shi[e] = *(const f32x2*)(sb + 100 + 2*e);
        }
      }
      const s16x8* XBf = (const s16x8*)buf;
      const s16x8* ASf = (const s16x8*)(buf + 5120);
      #pragma unroll
      for (int ks = 0; ks < 2; ++ks) {
        acc0 = __builtin_amdgcn_mfma_f32_16x16x32_bf16(
                 ASf[swz(n0*2+ks, l)], XBf[swz(n0*2+ks, l)], acc0, 0, 0, 0);
        acc1 = __builtin_amdgcn_mfma_f32_16x16x32_bf16(
                 ASf[swz(n1*2+ks, l)], XBf[swz(n1*2+ks, l)], acc1, 0, 0, 0);
      }
    } else if (tid == 320) {               // 6 power iters x 16 chunks = 96
      #pragma unroll
      for (int it = 0; it < 6; ++it) {
        float wv[5];
        #pragma unroll
        for (int r = 0; r < 5; ++r) {
          float s = 0.f;
          #pragma unroll
          for (int cc = 0; cc < 5; ++cc) s += pL[r][cc]*pv[cc];
          wv[r] = s;
        }
        float s = fabsf(wv[0])+fabsf(wv[1])+fabsf(wv[2])+fabsf(wv[3])+fabsf(wv[4]);
        float inv = 1.f/s;
        #pragma unroll
        for (int r = 0; r < 5; ++r) pv[r] = wv[r]*inv;
      }
    }
    lbar();                                // buf frag-reads done
    if (tid < 320 && c + 1 < NCHK) {       // stage chunk c+1
      #pragma unroll
      for (int r = 0; r < 4; ++r) {
        const int L = kgx*16 + th*4 + r;
        buf[swz((2*q  )*2 + ksx, L)*4 + jwx] = cvtpk(xlo[r].x, xhi[r].x);
        buf[swz((2*q+1)*2 + ksx, L)*4 + jwx] = cvtpk(xlo[r].y, xhi[r].y);
      }
      #pragma unroll
      for (int e = 0; e < 5; ++e) {
        const int L = kgx*16 + gq;
        buf[5120 + swz((2*e  )*2 + ksx, L)*4 + jwx] = cvtpk(slo[e].x, shi[e].x);
        buf[5120 + swz((2*e+1)*2 + ksx, L)*4 + jwx] = cvtpk(slo[e].y, shi[e].y);
      }
    }
  }

  // ---- finalize k0 -> ck
  if (tid == 320) {
    float num = 0.f, den = 0.f;
    #pragma unroll
    for (int r = 0; r < 5; ++r) {
      float s = 0.f;
      #pragma unroll
      for (int cc = 0; cc < 5; ++cc) s += pL[r][cc]*pv[cc];
      num += pv[r]*s; den += pv[r]*pv[r];
    }
    const float lam = num/den;
    float Lt[5][5], T2[5][5];
    #pragma unroll
    for (int r = 0; r < 5; ++r)
      #pragma unroll
      for (int cc = 0; cc < 5; ++cc)
        Lt[r][cc] = 2.f*pL[r][cc]/lam - (r==cc ? 1.f : 0.f);
    #pragma unroll
    for (int r = 0; r < 5; ++r)
      #pragma unroll
      for (int cc = 0; cc < 5; ++cc) {
        float s = 0.f;
        #pragma unroll
        for (int j = 0; j < 5; ++j) s += Lt[r][j]*Lt[j][cc];
        T2[r][cc] = 2.f*s - (r==cc ? 1.f : 0.f);
      }
    #pragma unroll
    for (int p = 0; p < 10; ++p)
      #pragma unroll
      for (int nn = 0; nn < 10; ++nn) {
        const int m = (10*p+nn) % 25, r = m/5, cc = m%5;
        ck[0*100 + p*10+nn] = (r==cc ? 1.f : 0.f);
        ck[1*100 + p*10+nn] = Lt[r][cc];
        ck[2*100 + p*10+nn] = T2[r][cc];
      }
  }
  // ---- acc -> S2 packed bf16 pairs: S2[t*52 + pp*10 + n] (t<8 valid only)
  if (tid < 320) {
    const int pg = (l >> 4) * 4;
    const int tl = l & 15;
    if (tl < TB) {
      unsigned* srow = S2 + tl*52;
      const int pp0 = pg >> 1;
      if (pg < 10) {
        srow[pp0*10 + n0] = cvtpk(acc0[0], acc0[1]);
        srow[pp0*10 + n1] = cvtpk(acc1[0], acc1[1]);
      }
      if (pg + 2 < 10) {
        srow[(pp0+1)*10 + n0] = cvtpk(acc0[2], acc0[3]);
        srow[(pp0+1)*10 + n1] = cvtpk(acc1[2], acc1[3]);
      }
    }
  }
  lbar();

  // ---- phase 2: out[t,b,n] = relu(sum_p S[n,p,t] * W[p,n,b])
  float* stg = (float*)buf;               // 2 x 5120 floats, double-buffered
  int pb = 0;
  for (int g = 0; g < 2; ++g) {
    const int b = g*512 + tid;
    float W[10][10];
    #pragma unroll
    for (int p = 0; p < 10; ++p) {
      const float th0 = theta[          p*NB + b];
      const float th1 = theta[10*NB  +  p*NB + b];
      const float th2 = theta[20*NB  +  p*NB + b];
      #pragma unroll
      for (int nn = 0; nn < 10; ++nn)
        W[p][nn] = ck[p*10+nn]*th0 + ck[100+p*10+nn]*th1 + ck[200+p*10+nn]*th2;
    }
    for (int t = 0; t < TB; ++t) {
      float a0[10];
      #pragma unroll
      for (int nn = 0; nn < 10; ++nn) a0[nn] = 0.f;
      {
        const uint4* rp = (const uint4*)(S2 + t*52);
        uint4 rq[13];
        #pragma unroll
        for (int i = 0; i < 13; ++i) rq[i] = rp[i];
        #pragma unroll
        for (int j = 0; j < 50; ++j) {
          const int i = j >> 2, e = j & 3;
          const unsigned u = (e==0) ? rq[i].x : (e==1) ? rq[i].y
                           : (e==2) ? rq[i].z : rq[i].w;
          const int pp = j / 10, nn = j - pp*10;
          a0[nn] += __uint_as_float(u << 16)         * W[2*pp][nn]
                  + __uint_as_float(u & 0xffff0000u) * W[2*pp+1][nn];
        }
      }
      float* sg = stg + pb*5120;
      #pragma unroll
      for (int nn = 0; nn < 10; ++nn)
        sg[tid*10 + nn] = fmaxf(a0[nn], 0.f);
      lbar();                             // sg visible; prior reads drained
      const f32x4* sv = (const f32x4*)sg;
      f32x4* op = (f32x4*)(out + (size_t)(t0 + t)*(NB*NS) + g*5120);
      __builtin_nontemporal_store(sv[tid],       op + tid);
      __builtin_nontemporal_store(sv[tid + 512], op + tid + 512);
      if (tid < 256)
        __builtin_nontemporal_store(sv[tid + 1024], op + tid + 1024);
      pb ^= 1;
    }
  }
}

extern "C" void kernel_launch(void* const* d_in, const int* in_sizes, int n_in,
                              void* d_out, int out_size, void* d_ws, size_t ws_size,
                              hipStream_t stream) {
  const float* x   = (const float*)d_in[0];  // (4096,1024,10)
  const float* adj = (const float*)d_in[1];  // (5,5)
  const float* sa  = (const float*)d_in[2];  // (1024,10,10)
  const float* th  = (const float*)d_in[3];  // (3,10,1024)
  float* out = (float*)d_out;
  hipLaunchKernelGGL(fused_k, dim3(TLEN/TB), dim3(512), 0, stream,
                     x, sa, adj, th, out);
}

// Round 20
// 85.470 us; speedup vs baseline: 1.7426x; 1.2506x over previous
//
#include <hip/hip_runtime.h>
#include <math.h>

#define TLEN 4096
#define NB   1024
#define NS   10
#define KC   64
#define NCHK 16
#define BUF_U32 10240   // XB 5120 | AS 5120 (u32 units, 40 KB)

typedef __attribute__((ext_vector_type(8))) short s16x8;
typedef __attribute__((ext_vector_type(4))) float f32x4;
typedef __attribute__((ext_vector_type(2))) float f32x2;

static __device__ __forceinline__ unsigned cvtpk(float lo, float hi) {
  unsigned r;
  asm("v_cvt_pk_bf16_f32 %0, %1, %2" : "=v"(r) : "v"(lo), "v"(hi));
  return r;
}
static __device__ __forceinline__ int swz(int P, int L) {
  return P*64 + (L ^ ((P ^ (P >> 2)) & 7));
}

// Fused: per block (t-tile of 16), S[n,p,t] = sum_b SA[b,p,n]*x[t,b,n] via
// MFMA over 16 K-chunks; then out[t,b,n] = relu(sum_p S * W[p,n,b]).
// Laplacian power-iteration runs on tid 320, 8 iters/chunk (hidden).
__global__ __launch_bounds__(512) void fused_k(
    const float* __restrict__ x, const float* __restrict__ sa,
    const float* __restrict__ adj, const float* __restrict__ theta,
    float* __restrict__ out) {
  __shared__ __align__(16) unsigned buf[BUF_U32];   // 40 KB; phase2: stg
  __shared__ __align__(16) float S[16*120];         // [t][n][12] padded
  __shared__ float ck[300];
  const int tid = threadIdx.x;
  const int l   = tid & 63;
  const int t0  = blockIdx.x * 16;

  if (tid >= 512) return;

  const int w   = tid >> 6;
  const int bp  = tid / 10;
  const int rm  = tid - bp*10;
  const int q   = rm >> 1;
  const int th  = rm & 1;
  const int gq  = rm;
  const int ksx = bp >> 4;
  const int kgx = (bp & 15) >> 2;
  const int jwx = bp & 3;
  const int n0  = 2*w, n1 = 2*w + 1;

  f32x4 acc0 = {0.f,0.f,0.f,0.f}, acc1 = {0.f,0.f,0.f,0.f};
  f32x2 xlo[8], xhi[8], slo[5], shi[5];

  // ---- k0 state (tid 320 only uses it)
  float pL[5][5], pv[5];
  if (tid == 320) {
    float Wm[5][5];
    #pragma unroll
    for (int r = 0; r < 5; ++r)
      #pragma unroll
      for (int c = 0; c < 5; ++c) Wm[r][c] = adj[r*5+c];
    #pragma unroll
    for (int r = 0; r < 5; ++r) {
      float d = 0.f;
      #pragma unroll
      for (int c = 0; c < 5; ++c) d += Wm[r][c];
      #pragma unroll
      for (int c = 0; c < 5; ++c) pL[r][c] = (r==c ? d : 0.f) - Wm[r][c];
    }
    pv[0]=0.7f; pv[1]=-1.1f; pv[2]=0.9f; pv[3]=-0.8f; pv[4]=1.3f;
  }

  // ---- prologue: load + stage chunk 0
  if (tid < 320) {
    const float* xb = x + (size_t)(t0 + th*8)*(NB*NS) + (size_t)(2*bp)*NS + 2*q;
    #pragma unroll
    for (int r = 0; r < 8; ++r) {
      xlo[r] = __builtin_nontemporal_load((const f32x2*)(xb + r*(NB*NS)));
      xhi[r] = __builtin_nontemporal_load((const f32x2*)(xb + r*(NB*NS) + NS));
    }
    const float* sb = sa + (size_t)(2*bp)*100 + gq*10;
    #pragma unroll
    for (int e = 0; e < 5; ++e) {
      slo[e] = *(const f32x2*)(sb + 2*e);
      shi[e] = *(const f32x2*)(sb + 100 + 2*e);
    }
    #pragma unroll
    for (int r = 0; r < 8; ++r) {
      const int L = kgx*16 + th*8 + r;
      buf[swz((2*q  )*2 + ksx, L)*4 + jwx] = cvtpk(xlo[r].x, xhi[r].x);
      buf[swz((2*q+1)*2 + ksx, L)*4 + jwx] = cvtpk(xlo[r].y, xhi[r].y);
    }
    #pragma unroll
    for (int e = 0; e < 5; ++e) {
      const int L = kgx*16 + gq;
      buf[5120 + swz((2*e  )*2 + ksx, L)*4 + jwx] = cvtpk(slo[e].x, shi[e].x);
      buf[5120 + swz((2*e+1)*2 + ksx, L)*4 + jwx] = cvtpk(slo[e].y, shi[e].y);
    }
  }

  for (int c = 0; c < NCHK; ++c) {
    __syncthreads();                       // staged writes visible
    if (tid < 320) {
      if (c + 1 < NCHK) {                  // issue next chunk's loads early
        const int bc = (c+1)*KC;
        const float* xb = x + (size_t)(t0 + th*8)*(NB*NS)
                            + (size_t)(bc + 2*bp)*NS + 2*q;
        #pragma unroll
        for (int r = 0; r < 8; ++r) {
          xlo[r] = __builtin_nontemporal_load((const f32x2*)(xb + r*(NB*NS)));
          xhi[r] = __builtin_nontemporal_load((const f32x2*)(xb + r*(NB*NS) + NS));
        }
        const float* sb = sa + (size_t)(bc + 2*bp)*100 + gq*10;
        #pragma unroll
        for (int e = 0; e < 5; ++e) {
          slo[e] = *(const f32x2*)(sb + 2*e);
          shi[e] = *(const f32x2*)(sb + 100 + 2*e);
        }
      }
      const s16x8* XBf = (const s16x8*)buf;
      const s16x8* ASf = (const s16x8*)(buf + 5120);
      #pragma unroll
      for (int ks = 0; ks < 2; ++ks) {
        acc0 = __builtin_amdgcn_mfma_f32_16x16x32_bf16(
                 ASf[swz(n0*2+ks, l)], XBf[swz(n0*2+ks, l)], acc0, 0, 0, 0);
        acc1 = __builtin_amdgcn_mfma_f32_16x16x32_bf16(
                 ASf[swz(n1*2+ks, l)], XBf[swz(n1*2+ks, l)], acc1, 0, 0, 0);
      }
    } else if (tid == 320 && c < 12) {     // 8 power iters per chunk (96 total)
      #pragma unroll
      for (int it = 0; it < 8; ++it) {
        float wv[5];
        #pragma unroll
        for (int r = 0; r < 5; ++r) {
          float s = 0.f;
          #pragma unroll
          for (int cc = 0; cc < 5; ++cc) s += pL[r][cc]*pv[cc];
          wv[r] = s;
        }
        float s = fabsf(wv[0])+fabsf(wv[1])+fabsf(wv[2])+fabsf(wv[3])+fabsf(wv[4]);
        float inv = 1.f/s;
        #pragma unroll
        for (int r = 0; r < 5; ++r) pv[r] = wv[r]*inv;
      }
    }
    __syncthreads();                       // buf reads done
    if (tid < 320 && c + 1 < NCHK) {       // stage chunk c+1
      #pragma unroll
      for (int r = 0; r < 8; ++r) {
        const int L = kgx*16 + th*8 + r;
        buf[swz((2*q  )*2 + ksx, L)*4 + jwx] = cvtpk(xlo[r].x, xhi[r].x);
        buf[swz((2*q+1)*2 + ksx, L)*4 + jwx] = cvtpk(xlo[r].y, xhi[r].y);
      }
      #pragma unroll
      for (int e = 0; e < 5; ++e) {
        const int L = kgx*16 + gq;
        buf[5120 + swz((2*e  )*2 + ksx, L)*4 + jwx] = cvtpk(slo[e].x, shi[e].x);
        buf[5120 + swz((2*e+1)*2 + ksx, L)*4 + jwx] = cvtpk(slo[e].y, shi[e].y);
      }
    }
  }

  // ---- finalize k0 -> ck (mostly hidden under S writes)
  if (tid == 320) {
    float num = 0.f, den = 0.f;
    #pragma unroll
    for (int r = 0; r < 5; ++r) {
      float s = 0.f;
      #pragma unroll
      for (int cc = 0; cc < 5; ++cc) s += pL[r][cc]*pv[cc];
      num += pv[r]*s; den += pv[r]*pv[r];
    }
    const float lam = num/den;
    float Lt[5][5], T2[5][5];
    #pragma unroll
    for (int r = 0; r < 5; ++r)
      #pragma unroll
      for (int cc = 0; cc < 5; ++cc)
        Lt[r][cc] = 2.f*pL[r][cc]/lam - (r==cc ? 1.f : 0.f);
    #pragma unroll
    for (int r = 0; r < 5; ++r)
      #pragma unroll
      for (int cc = 0; cc < 5; ++cc) {
        float s = 0.f;
        #pragma unroll
        for (int j = 0; j < 5; ++j) s += Lt[r][j]*Lt[j][cc];
        T2[r][cc] = 2.f*s - (r==cc ? 1.f : 0.f);
      }
    #pragma unroll
    for (int p = 0; p < 10; ++p)
      #pragma unroll
      for (int nn = 0; nn < 10; ++nn) {
        const int m = (10*p+nn) % 25, r = m/5, cc = m%5;
        ck[0*100 + p*10+nn] = (r==cc ? 1.f : 0.f);
        ck[1*100 + p*10+nn] = Lt[r][cc];
        ck[2*100 + p*10+nn] = T2[r][cc];
      }
  }
  // ---- acc -> S (C layout: col=lane&15 (t), row=(lane>>4)*4+reg (p))
  if (tid < 320) {
    const int pg = (l >> 4) * 4;
    const int tl = l & 15;
    #pragma unroll
    for (int r = 0; r < 4; ++r) {
      const int p = pg + r;
      if (p < 10) {
        S[tl*120 + n0*12 + p] = acc0[r];
        S[tl*120 + n1*12 + p] = acc1[r];
      }
    }
  }
  __syncthreads();

  // ---- phase 2: out[t,b,n] = relu(sum_p S[n,p,t] * W[p,n,b])
  float* stg = (float*)buf;               // 10240 floats = 2 t x 512 b x 10
  for (int g = 0; g < 2; ++g) {
    const int b = g*512 + tid;
    float W[10][10];
    #pragma unroll
    for (int p = 0; p < 10; ++p) {
      const float th0 = theta[          p*NB + b];
      const float th1 = theta[10*NB  +  p*NB + b];
      const float th2 = theta[20*NB  +  p*NB + b];
      #pragma unroll
      for (int nn = 0; nn < 10; ++nn)
        W[p][nn] = ck[p*10+nn]*th0 + ck[100+p*10+nn]*th1 + ck[200+p*10+nn]*th2;
    }
    for (int tp = 0; tp < 8; ++tp) {
      float a0[10], a1[10];
      #pragma unroll
      for (int nn = 0; nn < 10; ++nn) {
        const float4 s0 = *(const float4*)(S + (2*tp)*120 + nn*12);
        const float4 s1 = *(const float4*)(S + (2*tp)*120 + nn*12 + 4);
        const float2 s2 = *(const float2*)(S + (2*tp)*120 + nn*12 + 8);
        a0[nn] = s0.x*W[0][nn] + s0.y*W[1][nn] + s0.z*W[2][nn] + s0.w*W[3][nn]
               + s1.x*W[4][nn] + s1.y*W[5][nn] + s1.z*W[6][nn] + s1.w*W[7][nn]
               + s2.x*W[8][nn] + s2.y*W[9][nn];
        const float4 u0 = *(const float4*)(S + (2*tp+1)*120 + nn*12);
        const float4 u1 = *(const float4*)(S + (2*tp+1)*120 + nn*12 + 4);
        const float2 u2 = *(const float2*)(S + (2*tp+1)*120 + nn*12 + 8);
        a1[nn] = u0.x*W[0][nn] + u0.y*W[1][nn] + u0.z*W[2][nn] + u0.w*W[3][nn]
               + u1.x*W[4][nn] + u1.y*W[5][nn] + u1.z*W[6][nn] + u1.w*W[7][nn]
               + u2.x*W[8][nn] + u2.y*W[9][nn];
      }
      __syncthreads();                    // prev stores done reading stg
      #pragma unroll
      for (int nn = 0; nn < 10; ++nn) {
        stg[       tid*10 + nn] = fmaxf(a0[nn], 0.f);
        stg[5120 + tid*10 + nn] = fmaxf(a1[nn], 0.f);
      }
      __syncthreads();
      const f32x4* sv = (const f32x4*)stg;
      f32x4* op0 = (f32x4*)(out + (size_t)(t0 + 2*tp)*(NB*NS) + g*5120);
      f32x4* op1 = (f32x4*)(out + (size_t)(t0 + 2*tp + 1)*(NB*NS) + g*5120);
      __builtin_nontemporal_store(sv[tid],        op0 + tid);
      __builtin_nontemporal_store(sv[tid + 512],  op0 + tid + 512);
      if (tid < 256)
        __builtin_nontemporal_store(sv[tid + 1024], op0 + tid + 1024);
      __builtin_nontemporal_store(sv[tid + 1280], op1 + tid);
      __builtin_nontemporal_store(sv[tid + 1792], op1 + tid + 512);
      if (tid < 256)
        __builtin_nontemporal_store(sv[tid + 2304], op1 + tid + 1024);
    }
  }
}

extern "C" void kernel_launch(void* const* d_in, const int* in_sizes, int n_in,
                              void* d_out, int out_size, void* d_ws, size_t ws_size,
                              hipStream_t stream) {
  const float* x   = (const float*)d_in[0];  // (4096,1024,10)
  const float* adj = (const float*)d_in[1];  // (5,5)
  const float* sa  = (const float*)d_in[2];  // (1024,10,10)
  const float* th  = (const float*)d_in[3];  // (3,10,1024)
  float* out = (float*)d_out;
  hipLaunchKernelGGL(fused_k, dim3(TLEN/16), dim3(512), 0, stream,
                     x, sa, adj, th, out);
}